// Round 1
// baseline (591.142 us; speedup 1.0000x reference)
//
#include <hip/hip_runtime.h>

#define NEG_SLOPE 0.2f

// ---------------- CSR construction ----------------

__global__ void init_deg_kernel(int* __restrict__ deg, int* __restrict__ cursor, int n) {
    int i = blockIdx.x * blockDim.x + threadIdx.x;
    if (i < n) { deg[i] = 1; cursor[i] = 0; }  // deg starts at 1: self-loop
}

__global__ void count_kernel(const int* __restrict__ dst, int* __restrict__ deg, int E) {
    int i = blockIdx.x * blockDim.x + threadIdx.x;
    if (i < E) atomicAdd(&deg[dst[i]], 1);
}

// block-level inclusive scan (chunk = 256), writes per-block inclusive + block sums
__global__ void scanA_kernel(const int* __restrict__ deg, int* __restrict__ binc,
                             int* __restrict__ bsum, int n) {
    __shared__ int ws[4];
    int tid = threadIdx.x;
    int i = blockIdx.x * 256 + tid;
    int lane = tid & 63, wid = tid >> 6;
    int x = (i < n) ? deg[i] : 0;
    #pragma unroll
    for (int d = 1; d < 64; d <<= 1) { int t = __shfl_up(x, d); if (lane >= d) x += t; }
    if (lane == 63) ws[wid] = x;
    __syncthreads();
    int wofs = 0;
    for (int w = 0; w < wid; ++w) wofs += ws[w];
    x += wofs;
    if (i < n) binc[i] = x;
    if (tid == 255) bsum[blockIdx.x] = x;
}

// single-block inclusive scan of block sums, in place (handles arbitrary nb in chunks of 512)
__global__ void scanB_kernel(int* __restrict__ bsum, int nb) {
    __shared__ int ws[8];
    __shared__ int run_s;
    int tid = threadIdx.x;
    int lane = tid & 63, wid = tid >> 6;
    if (tid == 0) run_s = 0;
    __syncthreads();
    for (int base = 0; base < nb; base += 512) {
        int i = base + tid;
        int v = (i < nb) ? bsum[i] : 0;
        int x = v;
        #pragma unroll
        for (int d = 1; d < 64; d <<= 1) { int t = __shfl_up(x, d); if (lane >= d) x += t; }
        if (lane == 63) ws[wid] = x;
        __syncthreads();
        int wofs = 0;
        for (int w = 0; w < wid; ++w) wofs += ws[w];
        x += wofs;
        int run = run_s;
        if (i < nb) bsum[i] = x + run;
        __syncthreads();
        if (tid == 511) run_s = run + x;   // x at tid 511 == chunk total
        __syncthreads();
    }
}

__global__ void scanC_kernel(const int* __restrict__ binc, const int* __restrict__ bsumS,
                             int* __restrict__ off, int n) {
    int i = blockIdx.x * 256 + threadIdx.x;
    if (i < n) off[i + 1] = binc[i] + (blockIdx.x ? bsumS[blockIdx.x - 1] : 0);
    if (i == 0) off[0] = 0;
}

__global__ void fill_csr_kernel(const int* __restrict__ src, const int* __restrict__ dst,
                                const int* __restrict__ off, int* __restrict__ cursor,
                                int* __restrict__ csr, int E, int N) {
    int i = blockIdx.x * blockDim.x + threadIdx.x;
    int total = E + N;
    if (i >= total) return;
    int s, d;
    if (i < E) { s = src[i]; d = dst[i]; }
    else       { s = d = i - E; }          // self-loops
    int pos = atomicAdd(&cursor[d], 1);
    csr[off[d] + pos] = s;
}

// ---------------- h = X @ W, s = h.a_src, d = h.a_dst ----------------
// one wave per row; lane j owns output column j; W staged in LDS.

__global__ __launch_bounds__(256) void gemm_sd_kernel(
        const float* __restrict__ X, const float* __restrict__ W,
        const float* __restrict__ a_src, const float* __restrict__ a_dst,
        float* __restrict__ H, float* __restrict__ S, float* __restrict__ D, int n) {
    __shared__ float Wl[64 * 64];
    __shared__ float As[64], Ad[64];
    int tid = threadIdx.x;
    for (int i = tid; i < 64 * 64; i += 256) Wl[i] = W[i];
    if (tid < 64) { As[tid] = a_src[tid]; Ad[tid] = a_dst[tid]; }
    __syncthreads();
    int lane = tid & 63;
    int wave = tid >> 6;
    int row = blockIdx.x * 4 + wave;
    if (row >= n) return;
    float xv = X[row * 64 + lane];
    float acc = 0.f;
    #pragma unroll
    for (int k = 0; k < 64; ++k) {
        float xk = __shfl(xv, k);
        acc = fmaf(xk, Wl[k * 64 + lane], acc);
    }
    H[row * 64 + lane] = acc;
    float ps = acc * As[lane];
    float pd = acc * Ad[lane];
    #pragma unroll
    for (int o = 32; o > 0; o >>= 1) {
        ps += __shfl_xor(ps, o);
        pd += __shfl_xor(pd, o);
    }
    if (lane == 0) { S[row] = ps; D[row] = pd; }
}

// ---------------- per-node softmax + aggregate (gather, no atomics) ----------------
// one wave per dst node; lane = output dim.

__global__ __launch_bounds__(256) void aggregate_kernel(
        const float* __restrict__ H, const float* __restrict__ S, const float* __restrict__ D,
        const int* __restrict__ off, const int* __restrict__ csr,
        float* __restrict__ out, int n) {
    int wave = blockIdx.x * 4 + (threadIdx.x >> 6);
    int lane = threadIdx.x & 63;
    if (wave >= n) return;
    int v = wave;
    int beg = off[v], end = off[v + 1];
    float dv = D[v];
    // pass 1: segment max
    float m = -INFINITY;
    for (int j = beg + lane; j < end; j += 64) {
        float e = S[csr[j]] + dv;
        e = (e > 0.f) ? e : NEG_SLOPE * e;
        m = fmaxf(m, e);
    }
    #pragma unroll
    for (int o = 32; o > 0; o >>= 1) m = fmaxf(m, __shfl_xor(m, o));
    // pass 2: denom
    float dsum = 0.f;
    for (int j = beg + lane; j < end; j += 64) {
        float e = S[csr[j]] + dv;
        e = (e > 0.f) ? e : NEG_SLOPE * e;
        dsum += __expf(e - m);
    }
    #pragma unroll
    for (int o = 32; o > 0; o >>= 1) dsum += __shfl_xor(dsum, o);
    float inv = 1.f / dsum;
    // pass 3: weighted gather of source rows
    float acc = 0.f;
    for (int j = beg; j < end; ++j) {
        int s = csr[j];
        float e = S[s] + dv;
        e = (e > 0.f) ? e : NEG_SLOPE * e;
        float a = __expf(e - m) * inv;
        acc = fmaf(a, H[s * 64 + lane], acc);
    }
    out[v * 64 + lane] = acc;
}

// ---------------- driver ----------------

extern "C" void kernel_launch(void* const* d_in, const int* in_sizes, int n_in,
                              void* d_out, int out_size, void* d_ws, size_t ws_size,
                              hipStream_t stream) {
    const float* x   = (const float*)d_in[0];
    const int*   e   = (const int*)d_in[1];
    const float* W1  = (const float*)d_in[2];
    const float* as1 = (const float*)d_in[3];
    const float* ad1 = (const float*)d_in[4];
    const float* W2  = (const float*)d_in[5];
    const float* as2 = (const float*)d_in[6];
    const float* ad2 = (const float*)d_in[7];
    float* out = (float*)d_out;

    const int N = in_sizes[0] / 64;
    const int E = in_sizes[1] / 2;
    const int* src = e;
    const int* dst = e + E;

    // workspace layout
    float* h    = (float*)d_ws;          // N*64
    float* z1   = h + (size_t)N * 64;    // N*64
    float* S    = z1 + (size_t)N * 64;   // N
    float* D    = S + N;                 // N
    int* deg    = (int*)(D + N);         // N
    int* off    = deg + N;               // N+1
    int* cursor = off + N + 1;           // N
    int* csr    = cursor + N;            // E+N
    int* binc   = csr + (size_t)E + N;   // N
    int* bsum   = binc + N;              // nblk

    const int B = 256;
    int nblkN = (N + B - 1) / B;
    int nblkE = (E + B - 1) / B;
    int nblkT = (E + N + B - 1) / B;

    // CSR build (shared by both layers)
    init_deg_kernel<<<nblkN, B, 0, stream>>>(deg, cursor, N);
    count_kernel<<<nblkE, B, 0, stream>>>(dst, deg, E);
    scanA_kernel<<<nblkN, B, 0, stream>>>(deg, binc, bsum, N);
    scanB_kernel<<<1, 512, 0, stream>>>(bsum, nblkN);
    scanC_kernel<<<nblkN, B, 0, stream>>>(binc, bsum, off, N);
    fill_csr_kernel<<<nblkT, B, 0, stream>>>(src, dst, off, cursor, csr, E, N);

    int nblkW = (N + 3) / 4;  // one wave (64 lanes) per node/row, 4 waves per block

    // layer 1
    gemm_sd_kernel<<<nblkW, B, 0, stream>>>(x, W1, as1, ad1, h, S, D, N);
    aggregate_kernel<<<nblkW, B, 0, stream>>>(h, S, D, off, csr, z1, N);
    // layer 2
    gemm_sd_kernel<<<nblkW, B, 0, stream>>>(z1, W2, as2, ad2, h, S, D, N);
    aggregate_kernel<<<nblkW, B, 0, stream>>>(h, S, D, off, csr, out, N);
}

// Round 2
// 280.960 us; speedup vs baseline: 2.1040x; 2.1040x over previous
//
#include <hip/hip_runtime.h>

#define NEG_SLOPE 0.2f

// ---------------- CSR construction ----------------

__global__ void init_deg_kernel(int* __restrict__ deg, int* __restrict__ cursor, int n) {
    int i = blockIdx.x * blockDim.x + threadIdx.x;
    if (i < n) { deg[i] = 1; cursor[i] = 0; }  // deg starts at 1: self-loop
}

__global__ void count_kernel(const int* __restrict__ dst, int* __restrict__ deg, int E) {
    int i = blockIdx.x * blockDim.x + threadIdx.x;
    if (i < E) atomicAdd(&deg[dst[i]], 1);
}

// block-level inclusive scan (chunk = 256), writes per-block inclusive + block sums
__global__ void scanA_kernel(const int* __restrict__ deg, int* __restrict__ binc,
                             int* __restrict__ bsum, int n) {
    __shared__ int ws[4];
    int tid = threadIdx.x;
    int i = blockIdx.x * 256 + tid;
    int lane = tid & 63, wid = tid >> 6;
    int x = (i < n) ? deg[i] : 0;
    #pragma unroll
    for (int d = 1; d < 64; d <<= 1) { int t = __shfl_up(x, d); if (lane >= d) x += t; }
    if (lane == 63) ws[wid] = x;
    __syncthreads();
    int wofs = 0;
    for (int w = 0; w < wid; ++w) wofs += ws[w];
    x += wofs;
    if (i < n) binc[i] = x;
    if (tid == 255) bsum[blockIdx.x] = x;
}

// single-block inclusive scan of block sums, in place
__global__ void scanB_kernel(int* __restrict__ bsum, int nb) {
    __shared__ int ws[8];
    __shared__ int run_s;
    int tid = threadIdx.x;
    int lane = tid & 63, wid = tid >> 6;
    if (tid == 0) run_s = 0;
    __syncthreads();
    for (int base = 0; base < nb; base += 512) {
        int i = base + tid;
        int v = (i < nb) ? bsum[i] : 0;
        int x = v;
        #pragma unroll
        for (int d = 1; d < 64; d <<= 1) { int t = __shfl_up(x, d); if (lane >= d) x += t; }
        if (lane == 63) ws[wid] = x;
        __syncthreads();
        int wofs = 0;
        for (int w = 0; w < wid; ++w) wofs += ws[w];
        x += wofs;
        int run = run_s;
        if (i < nb) bsum[i] = x + run;
        __syncthreads();
        if (tid == 511) run_s = run + x;
        __syncthreads();
    }
}

__global__ void scanC_kernel(const int* __restrict__ binc, const int* __restrict__ bsumS,
                             int* __restrict__ off, int n) {
    int i = blockIdx.x * 256 + threadIdx.x;
    if (i < n) off[i + 1] = binc[i] + (blockIdx.x ? bsumS[blockIdx.x - 1] : 0);
    if (i == 0) off[0] = 0;
}

__global__ void fill_csr_kernel(const int* __restrict__ src, const int* __restrict__ dst,
                                const int* __restrict__ off, int* __restrict__ cursor,
                                int* __restrict__ csr, int E, int N) {
    int i = blockIdx.x * blockDim.x + threadIdx.x;
    int total = E + N;
    if (i >= total) return;
    int s, d;
    if (i < E) { s = src[i]; d = dst[i]; }
    else       { s = d = i - E; }          // self-loops
    int pos = atomicAdd(&cursor[d], 1);
    csr[off[d] + pos] = s;
}

// ---------------- H = X @ W  (tiled, 4x4 micro-tile) ----------------
// block = 256 threads computes a 64-row x 64-col tile.

__global__ __launch_bounds__(256) void gemm_kernel(
        const float* __restrict__ X, const float* __restrict__ W,
        float* __restrict__ H, int n) {
    __shared__ float Xs[64][65];   // +1 pad: conflict-free column reads
    __shared__ float Wl[64 * 64];
    int tid = threadIdx.x;
    int row0 = blockIdx.x * 64;

    {   // stage W (1024 float4)
        const float4* W4 = reinterpret_cast<const float4*>(W);
        float4* Wl4 = reinterpret_cast<float4*>(Wl);
        for (int i = tid; i < 1024; i += 256) Wl4[i] = W4[i];
    }
    {   // stage X tile
        for (int i = tid; i < 1024; i += 256) {
            int r = i >> 4;
            int c4 = (i & 15) * 4;
            int row = row0 + r;
            float4 xv = {0.f, 0.f, 0.f, 0.f};
            if (row < n) xv = *reinterpret_cast<const float4*>(&X[(size_t)row * 64 + c4]);
            Xs[r][c4 + 0] = xv.x; Xs[r][c4 + 1] = xv.y;
            Xs[r][c4 + 2] = xv.z; Xs[r][c4 + 3] = xv.w;
        }
    }
    __syncthreads();

    int c4 = (tid & 15) * 4;
    int r4 = (tid >> 4) * 4;
    float acc[4][4] = {};
    #pragma unroll 4
    for (int k = 0; k < 64; ++k) {
        float4 wv = *reinterpret_cast<const float4*>(&Wl[k * 64 + c4]);
        float x0 = Xs[r4 + 0][k];
        float x1 = Xs[r4 + 1][k];
        float x2 = Xs[r4 + 2][k];
        float x3 = Xs[r4 + 3][k];
        acc[0][0] = fmaf(x0, wv.x, acc[0][0]); acc[0][1] = fmaf(x0, wv.y, acc[0][1]);
        acc[0][2] = fmaf(x0, wv.z, acc[0][2]); acc[0][3] = fmaf(x0, wv.w, acc[0][3]);
        acc[1][0] = fmaf(x1, wv.x, acc[1][0]); acc[1][1] = fmaf(x1, wv.y, acc[1][1]);
        acc[1][2] = fmaf(x1, wv.z, acc[1][2]); acc[1][3] = fmaf(x1, wv.w, acc[1][3]);
        acc[2][0] = fmaf(x2, wv.x, acc[2][0]); acc[2][1] = fmaf(x2, wv.y, acc[2][1]);
        acc[2][2] = fmaf(x2, wv.z, acc[2][2]); acc[2][3] = fmaf(x2, wv.w, acc[2][3]);
        acc[3][0] = fmaf(x3, wv.x, acc[3][0]); acc[3][1] = fmaf(x3, wv.y, acc[3][1]);
        acc[3][2] = fmaf(x3, wv.z, acc[3][2]); acc[3][3] = fmaf(x3, wv.w, acc[3][3]);
    }
    #pragma unroll
    for (int i = 0; i < 4; ++i) {
        int row = row0 + r4 + i;
        if (row < n) {
            float4 o = { acc[i][0], acc[i][1], acc[i][2], acc[i][3] };
            *reinterpret_cast<float4*>(&H[(size_t)row * 64 + c4]) = o;
        }
    }
}

// ---------------- S = H.a_src, D = H.a_dst (row reduce) ----------------

__global__ __launch_bounds__(256) void sd_kernel(
        const float* __restrict__ H, const float* __restrict__ a_src,
        const float* __restrict__ a_dst,
        float* __restrict__ S, float* __restrict__ D, int n) {
    int row = blockIdx.x * 4 + (threadIdx.x >> 6);
    int lane = threadIdx.x & 63;
    if (row >= n) return;
    float h = H[(size_t)row * 64 + lane];
    float ps = h * a_src[lane];
    float pd = h * a_dst[lane];
    #pragma unroll
    for (int o = 32; o > 0; o >>= 1) {
        ps += __shfl_xor(ps, o);
        pd += __shfl_xor(pd, o);
    }
    if (lane == 0) { S[row] = ps; D[row] = pd; }
}

// ---------------- per-node softmax + aggregate (gather, no atomics) ----------------
// one wave per dst node; lane = (group g = lane>>4) x (t = lane&15, float4 of dims).
// fast path (deg <= 64): edge S-values loaded ONCE, weights kept in registers,
// broadcast via shfl; pass 3 processes 4 edges in parallel (1KB in flight/wave).

__global__ __launch_bounds__(256) void aggregate_kernel(
        const float* __restrict__ H, const float* __restrict__ S, const float* __restrict__ D,
        const int* __restrict__ off, const int* __restrict__ csr,
        float* __restrict__ out, int n) {
    int v = blockIdx.x * 4 + (threadIdx.x >> 6);
    int lane = threadIdx.x & 63;
    if (v >= n) return;
    int beg = off[v], end = off[v + 1];
    int deg = end - beg;
    float dv = D[v];
    int t = lane & 15, g = lane >> 4;
    float4 acc = {0.f, 0.f, 0.f, 0.f};

    if (deg <= 64) {
        int sreg = 0;
        float e = -INFINITY;
        if (lane < deg) {
            sreg = csr[beg + lane];
            e = S[sreg] + dv;
            e = (e > 0.f) ? e : NEG_SLOPE * e;
        }
        float m = e;
        #pragma unroll
        for (int o = 32; o > 0; o >>= 1) m = fmaxf(m, __shfl_xor(m, o));
        float w = (lane < deg) ? __expf(e - m) : 0.f;
        float dsum = w;
        #pragma unroll
        for (int o = 32; o > 0; o >>= 1) dsum += __shfl_xor(dsum, o);
        w *= (1.f / dsum);
        for (int base = 0; base < deg; base += 4) {
            int jj = base + g;
            int jidx = (jj < deg) ? jj : 0;
            float a = __shfl(w, jidx);
            int s = __shfl(sreg, jidx);
            if (jj < deg) {
                float4 hv = *reinterpret_cast<const float4*>(&H[(size_t)s * 64 + t * 4]);
                acc.x = fmaf(a, hv.x, acc.x);
                acc.y = fmaf(a, hv.y, acc.y);
                acc.z = fmaf(a, hv.z, acc.z);
                acc.w = fmaf(a, hv.w, acc.w);
            }
        }
    } else {
        // generic path (rare)
        float m = -INFINITY;
        for (int j = beg + lane; j < end; j += 64) {
            float e = S[csr[j]] + dv;
            e = (e > 0.f) ? e : NEG_SLOPE * e;
            m = fmaxf(m, e);
        }
        #pragma unroll
        for (int o = 32; o > 0; o >>= 1) m = fmaxf(m, __shfl_xor(m, o));
        float dsum = 0.f;
        for (int j = beg + lane; j < end; j += 64) {
            float e = S[csr[j]] + dv;
            e = (e > 0.f) ? e : NEG_SLOPE * e;
            dsum += __expf(e - m);
        }
        #pragma unroll
        for (int o = 32; o > 0; o >>= 1) dsum += __shfl_xor(dsum, o);
        float inv = 1.f / dsum;
        for (int base = 0; base < deg; base += 4) {
            int jj = base + g;
            if (jj < deg) {
                int s = csr[beg + jj];
                float e = S[s] + dv;
                e = (e > 0.f) ? e : NEG_SLOPE * e;
                float a = __expf(e - m) * inv;
                float4 hv = *reinterpret_cast<const float4*>(&H[(size_t)s * 64 + t * 4]);
                acc.x = fmaf(a, hv.x, acc.x);
                acc.y = fmaf(a, hv.y, acc.y);
                acc.z = fmaf(a, hv.z, acc.z);
                acc.w = fmaf(a, hv.w, acc.w);
            }
        }
    }
    // reduce across the 4 edge-groups (uniform control flow, full wave active)
    #pragma unroll
    for (int o = 16; o <= 32; o <<= 1) {
        acc.x += __shfl_xor(acc.x, o);
        acc.y += __shfl_xor(acc.y, o);
        acc.z += __shfl_xor(acc.z, o);
        acc.w += __shfl_xor(acc.w, o);
    }
    if (g == 0)
        *reinterpret_cast<float4*>(&out[(size_t)v * 64 + t * 4]) = acc;
}

// ---------------- driver ----------------

extern "C" void kernel_launch(void* const* d_in, const int* in_sizes, int n_in,
                              void* d_out, int out_size, void* d_ws, size_t ws_size,
                              hipStream_t stream) {
    const float* x   = (const float*)d_in[0];
    const int*   e   = (const int*)d_in[1];
    const float* W1  = (const float*)d_in[2];
    const float* as1 = (const float*)d_in[3];
    const float* ad1 = (const float*)d_in[4];
    const float* W2  = (const float*)d_in[5];
    const float* as2 = (const float*)d_in[6];
    const float* ad2 = (const float*)d_in[7];
    float* out = (float*)d_out;

    const int N = in_sizes[0] / 64;
    const int E = in_sizes[1] / 2;
    const int* src = e;
    const int* dst = e + E;

    // workspace layout
    float* h    = (float*)d_ws;          // N*64
    float* z1   = h + (size_t)N * 64;    // N*64
    float* S    = z1 + (size_t)N * 64;   // N
    float* D    = S + N;                 // N
    int* deg    = (int*)(D + N);         // N
    int* off    = deg + N;               // N+1
    int* cursor = off + N + 1;           // N
    int* csr    = cursor + N;            // E+N
    int* binc   = csr + (size_t)E + N;   // N
    int* bsum   = binc + N;              // nblk

    const int B = 256;
    int nblkN = (N + B - 1) / B;
    int nblkE = (E + B - 1) / B;
    int nblkT = (E + N + B - 1) / B;

    // CSR build (shared by both layers)
    init_deg_kernel<<<nblkN, B, 0, stream>>>(deg, cursor, N);
    count_kernel<<<nblkE, B, 0, stream>>>(dst, deg, E);
    scanA_kernel<<<nblkN, B, 0, stream>>>(deg, binc, bsum, N);
    scanB_kernel<<<1, 512, 0, stream>>>(bsum, nblkN);
    scanC_kernel<<<nblkN, B, 0, stream>>>(binc, bsum, off, N);
    fill_csr_kernel<<<nblkT, B, 0, stream>>>(src, dst, off, cursor, csr, E, N);

    int nblkG = (N + 63) / 64;   // gemm tiles
    int nblkW = (N + 3) / 4;     // wave-per-row kernels

    // layer 1
    gemm_kernel<<<nblkG, B, 0, stream>>>(x, W1, h, N);
    sd_kernel<<<nblkW, B, 0, stream>>>(h, as1, ad1, S, D, N);
    aggregate_kernel<<<nblkW, B, 0, stream>>>(h, S, D, off, csr, z1, N);
    // layer 2
    gemm_kernel<<<nblkG, B, 0, stream>>>(z1, W2, h, N);
    sd_kernel<<<nblkW, B, 0, stream>>>(h, as2, ad2, S, D, N);
    aggregate_kernel<<<nblkW, B, 0, stream>>>(h, S, D, off, csr, out, N);
}

// Round 4
// 214.787 us; speedup vs baseline: 2.7522x; 1.3081x over previous
//
#include <hip/hip_runtime.h>

#define NEG_SLOPE 0.2f

// ---------------- CSR construction ----------------
// Single atomic pass: each edge grabs its slot during counting.

__global__ void count_pos_kernel(const int* __restrict__ dst, int* __restrict__ deg,
                                 int* __restrict__ pos, int E) {
    int i = blockIdx.x * blockDim.x + threadIdx.x;
    if (i < E) pos[i] = atomicAdd(&deg[dst[i]], 1);
}

// block-level inclusive scan of (deg[i]+1) — +1 reserves the self-loop slot
__global__ void scanA_kernel(const int* __restrict__ deg, int* __restrict__ binc,
                             int* __restrict__ bsum, int n) {
    __shared__ int ws[4];
    int tid = threadIdx.x;
    int i = blockIdx.x * 256 + tid;
    int lane = tid & 63, wid = tid >> 6;
    int x = (i < n) ? (deg[i] + 1) : 0;
    #pragma unroll
    for (int d = 1; d < 64; d <<= 1) { int t = __shfl_up(x, d); if (lane >= d) x += t; }
    if (lane == 63) ws[wid] = x;
    __syncthreads();
    int wofs = 0;
    for (int w = 0; w < wid; ++w) wofs += ws[w];
    x += wofs;
    if (i < n) binc[i] = x;
    if (tid == 255) bsum[blockIdx.x] = x;
}

// single-block inclusive scan of block sums, in place
__global__ void scanB_kernel(int* __restrict__ bsum, int nb) {
    __shared__ int ws[8];
    __shared__ int run_s;
    int tid = threadIdx.x;
    int lane = tid & 63, wid = tid >> 6;
    if (tid == 0) run_s = 0;
    __syncthreads();
    for (int base = 0; base < nb; base += 512) {
        int i = base + tid;
        int v = (i < nb) ? bsum[i] : 0;
        int x = v;
        #pragma unroll
        for (int d = 1; d < 64; d <<= 1) { int t = __shfl_up(x, d); if (lane >= d) x += t; }
        if (lane == 63) ws[wid] = x;
        __syncthreads();
        int wofs = 0;
        for (int w = 0; w < wid; ++w) wofs += ws[w];
        x += wofs;
        int run = run_s;
        if (i < nb) bsum[i] = x + run;
        __syncthreads();
        if (tid == 511) run_s = run + x;
        __syncthreads();
    }
}

__global__ void scanC_kernel(const int* __restrict__ binc, const int* __restrict__ bsumS,
                             int* __restrict__ off, int n) {
    int i = blockIdx.x * 256 + threadIdx.x;
    if (i < n) off[i + 1] = binc[i] + (blockIdx.x ? bsumS[blockIdx.x - 1] : 0);
    if (i == 0) off[0] = 0;
}

// ---------------- fused: CSR fill (scatter, no atomics)  +  H = X@W with S/D epilogue ----
// blocks [0, nblkG): 64x64 GEMM tile; blocks [nblkG, ...): edge/self-loop scatter.
// The fill part is HBM-write-line bound; the GEMM rides under it for free.

__global__ __launch_bounds__(256) void gemm_fill_kernel(
        const float* __restrict__ X, const float* __restrict__ W,
        const float* __restrict__ a_src, const float* __restrict__ a_dst,
        float* __restrict__ H, float* __restrict__ S, float* __restrict__ D, int n,
        const int* __restrict__ src, const int* __restrict__ dst,
        const int* __restrict__ pos, const int* __restrict__ off,
        int* __restrict__ csr, int E, int nblkG) {
    __shared__ float Xs[64][65];   // +1 pad: conflict-free column reads
    __shared__ float Wl[64 * 64];

    if (blockIdx.x >= nblkG) {
        // ---- CSR fill ----
        int i = (blockIdx.x - nblkG) * 256 + threadIdx.x;
        int total = E + n;
        if (i >= total) return;
        if (i < E) {
            csr[off[dst[i]] + pos[i]] = src[i];
        } else {
            int v = i - E;
            csr[off[v + 1] - 1] = v;     // self-loop in the reserved last slot
        }
        return;
    }

    // ---- GEMM tile ----
    int tid = threadIdx.x;
    int row0 = blockIdx.x * 64;
    {
        const float4* W4 = reinterpret_cast<const float4*>(W);
        float4* Wl4 = reinterpret_cast<float4*>(Wl);
        for (int i = tid; i < 1024; i += 256) Wl4[i] = W4[i];
    }
    {
        for (int i = tid; i < 1024; i += 256) {
            int r = i >> 4;
            int c4 = (i & 15) * 4;
            int row = row0 + r;
            float4 xv = {0.f, 0.f, 0.f, 0.f};
            if (row < n) xv = *reinterpret_cast<const float4*>(&X[(size_t)row * 64 + c4]);
            Xs[r][c4 + 0] = xv.x; Xs[r][c4 + 1] = xv.y;
            Xs[r][c4 + 2] = xv.z; Xs[r][c4 + 3] = xv.w;
        }
    }
    __syncthreads();

    int c4 = (tid & 15) * 4;
    int r4 = (tid >> 4) * 4;
    float acc[4][4] = {};
    #pragma unroll 4
    for (int k = 0; k < 64; ++k) {
        float4 wv = *reinterpret_cast<const float4*>(&Wl[k * 64 + c4]);
        float x0 = Xs[r4 + 0][k];
        float x1 = Xs[r4 + 1][k];
        float x2 = Xs[r4 + 2][k];
        float x3 = Xs[r4 + 3][k];
        acc[0][0] = fmaf(x0, wv.x, acc[0][0]); acc[0][1] = fmaf(x0, wv.y, acc[0][1]);
        acc[0][2] = fmaf(x0, wv.z, acc[0][2]); acc[0][3] = fmaf(x0, wv.w, acc[0][3]);
        acc[1][0] = fmaf(x1, wv.x, acc[1][0]); acc[1][1] = fmaf(x1, wv.y, acc[1][1]);
        acc[1][2] = fmaf(x1, wv.z, acc[1][2]); acc[1][3] = fmaf(x1, wv.w, acc[1][3]);
        acc[2][0] = fmaf(x2, wv.x, acc[2][0]); acc[2][1] = fmaf(x2, wv.y, acc[2][1]);
        acc[2][2] = fmaf(x2, wv.z, acc[2][2]); acc[2][3] = fmaf(x2, wv.w, acc[2][3]);
        acc[3][0] = fmaf(x3, wv.x, acc[3][0]); acc[3][1] = fmaf(x3, wv.y, acc[3][1]);
        acc[3][2] = fmaf(x3, wv.z, acc[3][2]); acc[3][3] = fmaf(x3, wv.w, acc[3][3]);
    }
    #pragma unroll
    for (int i = 0; i < 4; ++i) {
        int row = row0 + r4 + i;
        if (row < n) {
            float4 o = { acc[i][0], acc[i][1], acc[i][2], acc[i][3] };
            *reinterpret_cast<float4*>(&H[(size_t)row * 64 + c4]) = o;
        }
    }
    // ---- S/D epilogue: per-row dots with a_src/a_dst, reduce over 16 col-threads ----
    float4 av = *reinterpret_cast<const float4*>(&a_src[c4]);
    float4 bv = *reinterpret_cast<const float4*>(&a_dst[c4]);
    #pragma unroll
    for (int i = 0; i < 4; ++i) {
        float ps = acc[i][0] * av.x + acc[i][1] * av.y + acc[i][2] * av.z + acc[i][3] * av.w;
        float pd = acc[i][0] * bv.x + acc[i][1] * bv.y + acc[i][2] * bv.z + acc[i][3] * bv.w;
        #pragma unroll
        for (int o = 1; o < 16; o <<= 1) {   // xor within the aligned 16-lane row group
            ps += __shfl_xor(ps, o);
            pd += __shfl_xor(pd, o);
        }
        int row = row0 + r4 + i;
        if ((tid & 15) == 0 && row < n) { S[row] = ps; D[row] = pd; }
    }
}

// ---------------- plain GEMM + S/D (layer 2; no fill partner) ----------------

__global__ __launch_bounds__(256) void gemm_sd_kernel(
        const float* __restrict__ X, const float* __restrict__ W,
        const float* __restrict__ a_src, const float* __restrict__ a_dst,
        float* __restrict__ H, float* __restrict__ S, float* __restrict__ D, int n) {
    __shared__ float Xs[64][65];
    __shared__ float Wl[64 * 64];
    int tid = threadIdx.x;
    int row0 = blockIdx.x * 64;
    {
        const float4* W4 = reinterpret_cast<const float4*>(W);
        float4* Wl4 = reinterpret_cast<float4*>(Wl);
        for (int i = tid; i < 1024; i += 256) Wl4[i] = W4[i];
    }
    {
        for (int i = tid; i < 1024; i += 256) {
            int r = i >> 4;
            int c4 = (i & 15) * 4;
            int row = row0 + r;
            float4 xv = {0.f, 0.f, 0.f, 0.f};
            if (row < n) xv = *reinterpret_cast<const float4*>(&X[(size_t)row * 64 + c4]);
            Xs[r][c4 + 0] = xv.x; Xs[r][c4 + 1] = xv.y;
            Xs[r][c4 + 2] = xv.z; Xs[r][c4 + 3] = xv.w;
        }
    }
    __syncthreads();
    int c4 = (tid & 15) * 4;
    int r4 = (tid >> 4) * 4;
    float acc[4][4] = {};
    #pragma unroll 4
    for (int k = 0; k < 64; ++k) {
        float4 wv = *reinterpret_cast<const float4*>(&Wl[k * 64 + c4]);
        float x0 = Xs[r4 + 0][k];
        float x1 = Xs[r4 + 1][k];
        float x2 = Xs[r4 + 2][k];
        float x3 = Xs[r4 + 3][k];
        acc[0][0] = fmaf(x0, wv.x, acc[0][0]); acc[0][1] = fmaf(x0, wv.y, acc[0][1]);
        acc[0][2] = fmaf(x0, wv.z, acc[0][2]); acc[0][3] = fmaf(x0, wv.w, acc[0][3]);
        acc[1][0] = fmaf(x1, wv.x, acc[1][0]); acc[1][1] = fmaf(x1, wv.y, acc[1][1]);
        acc[1][2] = fmaf(x1, wv.z, acc[1][2]); acc[1][3] = fmaf(x1, wv.w, acc[1][3]);
        acc[2][0] = fmaf(x2, wv.x, acc[2][0]); acc[2][1] = fmaf(x2, wv.y, acc[2][1]);
        acc[2][2] = fmaf(x2, wv.z, acc[2][2]); acc[2][3] = fmaf(x2, wv.w, acc[2][3]);
        acc[3][0] = fmaf(x3, wv.x, acc[3][0]); acc[3][1] = fmaf(x3, wv.y, acc[3][1]);
        acc[3][2] = fmaf(x3, wv.z, acc[3][2]); acc[3][3] = fmaf(x3, wv.w, acc[3][3]);
    }
    #pragma unroll
    for (int i = 0; i < 4; ++i) {
        int row = row0 + r4 + i;
        if (row < n) {
            float4 o = { acc[i][0], acc[i][1], acc[i][2], acc[i][3] };
            *reinterpret_cast<float4*>(&H[(size_t)row * 64 + c4]) = o;
        }
    }
    float4 av = *reinterpret_cast<const float4*>(&a_src[c4]);
    float4 bv = *reinterpret_cast<const float4*>(&a_dst[c4]);
    #pragma unroll
    for (int i = 0; i < 4; ++i) {
        float ps = acc[i][0] * av.x + acc[i][1] * av.y + acc[i][2] * av.z + acc[i][3] * av.w;
        float pd = acc[i][0] * bv.x + acc[i][1] * bv.y + acc[i][2] * bv.z + acc[i][3] * bv.w;
        #pragma unroll
        for (int o = 1; o < 16; o <<= 1) {
            ps += __shfl_xor(ps, o);
            pd += __shfl_xor(pd, o);
        }
        int row = row0 + r4 + i;
        if ((tid & 15) == 0 && row < n) { S[row] = ps; D[row] = pd; }
    }
}

// ---------------- per-node softmax + aggregate (gather, no atomics) ----------------

__global__ __launch_bounds__(256) void aggregate_kernel(
        const float* __restrict__ H, const float* __restrict__ S, const float* __restrict__ D,
        const int* __restrict__ off, const int* __restrict__ csr,
        float* __restrict__ out, int n) {
    int v = blockIdx.x * 4 + (threadIdx.x >> 6);
    int lane = threadIdx.x & 63;
    if (v >= n) return;
    int beg = off[v], end = off[v + 1];
    int deg = end - beg;
    float dv = D[v];
    int t = lane & 15, g = lane >> 4;
    float4 acc = {0.f, 0.f, 0.f, 0.f};

    if (deg <= 64) {
        int sreg = 0;
        float e = -INFINITY;
        if (lane < deg) {
            sreg = csr[beg + lane];
            e = S[sreg] + dv;
            e = (e > 0.f) ? e : NEG_SLOPE * e;
        }
        float m = e;
        #pragma unroll
        for (int o = 32; o > 0; o >>= 1) m = fmaxf(m, __shfl_xor(m, o));
        float w = (lane < deg) ? __expf(e - m) : 0.f;
        float dsum = w;
        #pragma unroll
        for (int o = 32; o > 0; o >>= 1) dsum += __shfl_xor(dsum, o);
        w *= (1.f / dsum);
        for (int base = 0; base < deg; base += 4) {
            int jj = base + g;
            int jidx = (jj < deg) ? jj : 0;
            float a = __shfl(w, jidx);
            int s = __shfl(sreg, jidx);
            if (jj < deg) {
                float4 hv = *reinterpret_cast<const float4*>(&H[(size_t)s * 64 + t * 4]);
                acc.x = fmaf(a, hv.x, acc.x);
                acc.y = fmaf(a, hv.y, acc.y);
                acc.z = fmaf(a, hv.z, acc.z);
                acc.w = fmaf(a, hv.w, acc.w);
            }
        }
    } else {
        float m = -INFINITY;
        for (int j = beg + lane; j < end; j += 64) {
            float e = S[csr[j]] + dv;
            e = (e > 0.f) ? e : NEG_SLOPE * e;
            m = fmaxf(m, e);
        }
        #pragma unroll
        for (int o = 32; o > 0; o >>= 1) m = fmaxf(m, __shfl_xor(m, o));
        float dsum = 0.f;
        for (int j = beg + lane; j < end; j += 64) {
            float e = S[csr[j]] + dv;
            e = (e > 0.f) ? e : NEG_SLOPE * e;
            dsum += __expf(e - m);
        }
        #pragma unroll
        for (int o = 32; o > 0; o >>= 1) dsum += __shfl_xor(dsum, o);
        float inv = 1.f / dsum;
        for (int base = 0; base < deg; base += 4) {
            int jj = base + g;
            if (jj < deg) {
                int s = csr[beg + jj];
                float e = S[s] + dv;
                e = (e > 0.f) ? e : NEG_SLOPE * e;
                float a = __expf(e - m) * inv;
                float4 hv = *reinterpret_cast<const float4*>(&H[(size_t)s * 64 + t * 4]);
                acc.x = fmaf(a, hv.x, acc.x);
                acc.y = fmaf(a, hv.y, acc.y);
                acc.z = fmaf(a, hv.z, acc.z);
                acc.w = fmaf(a, hv.w, acc.w);
            }
        }
    }
    #pragma unroll
    for (int o = 16; o <= 32; o <<= 1) {
        acc.x += __shfl_xor(acc.x, o);
        acc.y += __shfl_xor(acc.y, o);
        acc.z += __shfl_xor(acc.z, o);
        acc.w += __shfl_xor(acc.w, o);
    }
    if (g == 0)
        *reinterpret_cast<float4*>(&out[(size_t)v * 64 + t * 4]) = acc;
}

// ---------------- driver ----------------

extern "C" void kernel_launch(void* const* d_in, const int* in_sizes, int n_in,
                              void* d_out, int out_size, void* d_ws, size_t ws_size,
                              hipStream_t stream) {
    const float* x   = (const float*)d_in[0];
    const int*   e   = (const int*)d_in[1];
    const float* W1  = (const float*)d_in[2];
    const float* as1 = (const float*)d_in[3];
    const float* ad1 = (const float*)d_in[4];
    const float* W2  = (const float*)d_in[5];
    const float* as2 = (const float*)d_in[6];
    const float* ad2 = (const float*)d_in[7];
    float* out = (float*)d_out;

    const int N = in_sizes[0] / 64;
    const int E = in_sizes[1] / 2;
    const int* src = e;
    const int* dst = e + E;

    // workspace layout (~36 MB)
    float* h    = (float*)d_ws;          // N*64
    float* S    = h + (size_t)N * 64;    // N
    float* D    = S + N;                 // N
    int* deg    = (int*)(D + N);         // N
    int* off    = deg + N;               // N+1
    int* pos    = off + N + 1;           // E
    int* csr    = pos + E;               // E+N
    int* binc   = csr + (size_t)E + N;   // N
    int* bsum   = binc + N;              // nblkN
    float* z1   = out;                   // layer-1 activations live in d_out

    const int B = 256;
    int nblkN = (N + B - 1) / B;
    int nblkE = (E + B - 1) / B;
    int nblkT = (E + N + B - 1) / B;
    int nblkG = (N + 63) / 64;
    int nblkW = (N + 3) / 4;

    // CSR: count (+slot assignment) -> scan -> [fill || gemm1]
    hipMemsetAsync(deg, 0, (size_t)N * sizeof(int), stream);
    count_pos_kernel<<<nblkE, B, 0, stream>>>(dst, deg, pos, E);
    scanA_kernel<<<nblkN, B, 0, stream>>>(deg, binc, bsum, N);
    scanB_kernel<<<1, 512, 0, stream>>>(bsum, nblkN);
    scanC_kernel<<<nblkN, B, 0, stream>>>(binc, bsum, off, N);

    gemm_fill_kernel<<<nblkG + nblkT, B, 0, stream>>>(
        x, W1, as1, ad1, h, S, D, N, src, dst, pos, off, csr, E, nblkG);

    aggregate_kernel<<<nblkW, B, 0, stream>>>(h, S, D, off, csr, z1, N);
    gemm_sd_kernel<<<nblkG, B, 0, stream>>>(z1, W2, as2, ad2, h, S, D, N);
    aggregate_kernel<<<nblkW, B, 0, stream>>>(h, S, D, off, csr, out, N);
}

// Round 5
// 204.290 us; speedup vs baseline: 2.8936x; 1.0514x over previous
//
#include <hip/hip_runtime.h>

#define NEG_SLOPE 0.2f

typedef unsigned int uint32;

// round-to-nearest-even pack of two floats into 2x bf16 in one uint
__device__ __forceinline__ uint32 pack2bf(float a, float b) {
    uint32 ua = __float_as_uint(a);
    uint32 ub = __float_as_uint(b);
    ua += 0x7fffu + ((ua >> 16) & 1u);
    ub += 0x7fffu + ((ub >> 16) & 1u);
    return (ua >> 16) | (ub & 0xffff0000u);
}

// ---------------- CSR construction ----------------
// Single atomic pass: each edge grabs its slot during counting.

__global__ void count_pos_kernel(const int* __restrict__ dst, int* __restrict__ deg,
                                 int* __restrict__ pos, int E) {
    int i = blockIdx.x * blockDim.x + threadIdx.x;
    if (i < E) pos[i] = atomicAdd(&deg[dst[i]], 1);
}

// block-level inclusive scan of (deg[i]+1) — +1 reserves the self-loop slot
__global__ void scanA_kernel(const int* __restrict__ deg, int* __restrict__ binc,
                             int* __restrict__ bsum, int n) {
    __shared__ int ws[4];
    int tid = threadIdx.x;
    int i = blockIdx.x * 256 + tid;
    int lane = tid & 63, wid = tid >> 6;
    int x = (i < n) ? (deg[i] + 1) : 0;
    #pragma unroll
    for (int d = 1; d < 64; d <<= 1) { int t = __shfl_up(x, d); if (lane >= d) x += t; }
    if (lane == 63) ws[wid] = x;
    __syncthreads();
    int wofs = 0;
    for (int w = 0; w < wid; ++w) wofs += ws[w];
    x += wofs;
    if (i < n) binc[i] = x;
    if (tid == 255) bsum[blockIdx.x] = x;
}

// single-block inclusive scan of block sums, in place
__global__ void scanB_kernel(int* __restrict__ bsum, int nb) {
    __shared__ int ws[8];
    __shared__ int run_s;
    int tid = threadIdx.x;
    int lane = tid & 63, wid = tid >> 6;
    if (tid == 0) run_s = 0;
    __syncthreads();
    for (int base = 0; base < nb; base += 512) {
        int i = base + tid;
        int v = (i < nb) ? bsum[i] : 0;
        int x = v;
        #pragma unroll
        for (int d = 1; d < 64; d <<= 1) { int t = __shfl_up(x, d); if (lane >= d) x += t; }
        if (lane == 63) ws[wid] = x;
        __syncthreads();
        int wofs = 0;
        for (int w = 0; w < wid; ++w) wofs += ws[w];
        x += wofs;
        int run = run_s;
        if (i < nb) bsum[i] = x + run;
        __syncthreads();
        if (tid == 511) run_s = run + x;
        __syncthreads();
    }
}

__global__ void scanC_kernel(const int* __restrict__ binc, const int* __restrict__ bsumS,
                             int* __restrict__ off, int n) {
    int i = blockIdx.x * 256 + threadIdx.x;
    if (i < n) off[i + 1] = binc[i] + (blockIdx.x ? bsumS[blockIdx.x - 1] : 0);
    if (i == 0) off[0] = 0;
}

// ---------------- fused: CSR fill (scatter)  +  H(bf16) = X@W with S/D epilogue ----
// blocks [0, nblkG): 64x64 GEMM tile; blocks [nblkG, ...): edge/self-loop scatter.

__global__ __launch_bounds__(256) void gemm_fill_kernel(
        const float* __restrict__ X, const float* __restrict__ W,
        const float* __restrict__ a_src, const float* __restrict__ a_dst,
        uint32* __restrict__ Hb, float* __restrict__ S, float* __restrict__ D, int n,
        const int* __restrict__ src, const int* __restrict__ dst,
        const int* __restrict__ pos, const int* __restrict__ off,
        int* __restrict__ csr, int E, int nblkG) {
    __shared__ float Xs[64][65];   // +1 pad: conflict-free column reads
    __shared__ float Wl[64 * 64];

    if (blockIdx.x >= nblkG) {
        // ---- CSR fill ----
        int i = (blockIdx.x - nblkG) * 256 + threadIdx.x;
        int total = E + n;
        if (i >= total) return;
        if (i < E) {
            csr[off[dst[i]] + pos[i]] = src[i];
        } else {
            int v = i - E;
            csr[off[v + 1] - 1] = v;     // self-loop in the reserved last slot
        }
        return;
    }

    // ---- GEMM tile ----
    int tid = threadIdx.x;
    int row0 = blockIdx.x * 64;
    {
        const float4* W4 = reinterpret_cast<const float4*>(W);
        float4* Wl4 = reinterpret_cast<float4*>(Wl);
        for (int i = tid; i < 1024; i += 256) Wl4[i] = W4[i];
    }
    {
        for (int i = tid; i < 1024; i += 256) {
            int r = i >> 4;
            int c4 = (i & 15) * 4;
            int row = row0 + r;
            float4 xv = {0.f, 0.f, 0.f, 0.f};
            if (row < n) xv = *reinterpret_cast<const float4*>(&X[(size_t)row * 64 + c4]);
            Xs[r][c4 + 0] = xv.x; Xs[r][c4 + 1] = xv.y;
            Xs[r][c4 + 2] = xv.z; Xs[r][c4 + 3] = xv.w;
        }
    }
    __syncthreads();

    int c4 = (tid & 15) * 4;
    int r4 = (tid >> 4) * 4;
    float acc[4][4] = {};
    #pragma unroll 4
    for (int k = 0; k < 64; ++k) {
        float4 wv = *reinterpret_cast<const float4*>(&Wl[k * 64 + c4]);
        float x0 = Xs[r4 + 0][k];
        float x1 = Xs[r4 + 1][k];
        float x2 = Xs[r4 + 2][k];
        float x3 = Xs[r4 + 3][k];
        acc[0][0] = fmaf(x0, wv.x, acc[0][0]); acc[0][1] = fmaf(x0, wv.y, acc[0][1]);
        acc[0][2] = fmaf(x0, wv.z, acc[0][2]); acc[0][3] = fmaf(x0, wv.w, acc[0][3]);
        acc[1][0] = fmaf(x1, wv.x, acc[1][0]); acc[1][1] = fmaf(x1, wv.y, acc[1][1]);
        acc[1][2] = fmaf(x1, wv.z, acc[1][2]); acc[1][3] = fmaf(x1, wv.w, acc[1][3]);
        acc[2][0] = fmaf(x2, wv.x, acc[2][0]); acc[2][1] = fmaf(x2, wv.y, acc[2][1]);
        acc[2][2] = fmaf(x2, wv.z, acc[2][2]); acc[2][3] = fmaf(x2, wv.w, acc[2][3]);
        acc[3][0] = fmaf(x3, wv.x, acc[3][0]); acc[3][1] = fmaf(x3, wv.y, acc[3][1]);
        acc[3][2] = fmaf(x3, wv.z, acc[3][2]); acc[3][3] = fmaf(x3, wv.w, acc[3][3]);
    }
    #pragma unroll
    for (int i = 0; i < 4; ++i) {
        int row = row0 + r4 + i;
        if (row < n) {
            uint2 p;
            p.x = pack2bf(acc[i][0], acc[i][1]);
            p.y = pack2bf(acc[i][2], acc[i][3]);
            *reinterpret_cast<uint2*>(&Hb[(size_t)row * 32 + (c4 >> 1)]) = p;
        }
    }
    // ---- S/D epilogue ----
    float4 av = *reinterpret_cast<const float4*>(&a_src[c4]);
    float4 bv = *reinterpret_cast<const float4*>(&a_dst[c4]);
    #pragma unroll
    for (int i = 0; i < 4; ++i) {
        float ps = acc[i][0] * av.x + acc[i][1] * av.y + acc[i][2] * av.z + acc[i][3] * av.w;
        float pd = acc[i][0] * bv.x + acc[i][1] * bv.y + acc[i][2] * bv.z + acc[i][3] * bv.w;
        #pragma unroll
        for (int o = 1; o < 16; o <<= 1) {
            ps += __shfl_xor(ps, o);
            pd += __shfl_xor(pd, o);
        }
        int row = row0 + r4 + i;
        if ((tid & 15) == 0 && row < n) { S[row] = ps; D[row] = pd; }
    }
}

// ---------------- plain GEMM + S/D (layer 2) ----------------

__global__ __launch_bounds__(256) void gemm_sd_kernel(
        const float* __restrict__ X, const float* __restrict__ W,
        const float* __restrict__ a_src, const float* __restrict__ a_dst,
        uint32* __restrict__ Hb, float* __restrict__ S, float* __restrict__ D, int n) {
    __shared__ float Xs[64][65];
    __shared__ float Wl[64 * 64];
    int tid = threadIdx.x;
    int row0 = blockIdx.x * 64;
    {
        const float4* W4 = reinterpret_cast<const float4*>(W);
        float4* Wl4 = reinterpret_cast<float4*>(Wl);
        for (int i = tid; i < 1024; i += 256) Wl4[i] = W4[i];
    }
    {
        for (int i = tid; i < 1024; i += 256) {
            int r = i >> 4;
            int c4 = (i & 15) * 4;
            int row = row0 + r;
            float4 xv = {0.f, 0.f, 0.f, 0.f};
            if (row < n) xv = *reinterpret_cast<const float4*>(&X[(size_t)row * 64 + c4]);
            Xs[r][c4 + 0] = xv.x; Xs[r][c4 + 1] = xv.y;
            Xs[r][c4 + 2] = xv.z; Xs[r][c4 + 3] = xv.w;
        }
    }
    __syncthreads();
    int c4 = (tid & 15) * 4;
    int r4 = (tid >> 4) * 4;
    float acc[4][4] = {};
    #pragma unroll 4
    for (int k = 0; k < 64; ++k) {
        float4 wv = *reinterpret_cast<const float4*>(&Wl[k * 64 + c4]);
        float x0 = Xs[r4 + 0][k];
        float x1 = Xs[r4 + 1][k];
        float x2 = Xs[r4 + 2][k];
        float x3 = Xs[r4 + 3][k];
        acc[0][0] = fmaf(x0, wv.x, acc[0][0]); acc[0][1] = fmaf(x0, wv.y, acc[0][1]);
        acc[0][2] = fmaf(x0, wv.z, acc[0][2]); acc[0][3] = fmaf(x0, wv.w, acc[0][3]);
        acc[1][0] = fmaf(x1, wv.x, acc[1][0]); acc[1][1] = fmaf(x1, wv.y, acc[1][1]);
        acc[1][2] = fmaf(x1, wv.z, acc[1][2]); acc[1][3] = fmaf(x1, wv.w, acc[1][3]);
        acc[2][0] = fmaf(x2, wv.x, acc[2][0]); acc[2][1] = fmaf(x2, wv.y, acc[2][1]);
        acc[2][2] = fmaf(x2, wv.z, acc[2][2]); acc[2][3] = fmaf(x2, wv.w, acc[2][3]);
        acc[3][0] = fmaf(x3, wv.x, acc[3][0]); acc[3][1] = fmaf(x3, wv.y, acc[3][1]);
        acc[3][2] = fmaf(x3, wv.z, acc[3][2]); acc[3][3] = fmaf(x3, wv.w, acc[3][3]);
    }
    #pragma unroll
    for (int i = 0; i < 4; ++i) {
        int row = row0 + r4 + i;
        if (row < n) {
            uint2 p;
            p.x = pack2bf(acc[i][0], acc[i][1]);
            p.y = pack2bf(acc[i][2], acc[i][3]);
            *reinterpret_cast<uint2*>(&Hb[(size_t)row * 32 + (c4 >> 1)]) = p;
        }
    }
    float4 av = *reinterpret_cast<const float4*>(&a_src[c4]);
    float4 bv = *reinterpret_cast<const float4*>(&a_dst[c4]);
    #pragma unroll
    for (int i = 0; i < 4; ++i) {
        float ps = acc[i][0] * av.x + acc[i][1] * av.y + acc[i][2] * av.z + acc[i][3] * av.w;
        float pd = acc[i][0] * bv.x + acc[i][1] * bv.y + acc[i][2] * bv.z + acc[i][3] * bv.w;
        #pragma unroll
        for (int o = 1; o < 16; o <<= 1) {
            ps += __shfl_xor(ps, o);
            pd += __shfl_xor(pd, o);
        }
        int row = row0 + r4 + i;
        if ((tid & 15) == 0 && row < n) { S[row] = ps; D[row] = pd; }
    }
}

// ---------------- per-node softmax + aggregate (bf16 gather, 8 edges in flight) ----
// one wave per dst node; lane = (group g = lane>>3) x (t = lane&7, 8 bf16 dims).

__global__ __launch_bounds__(256) void aggregate_kernel(
        const uint32* __restrict__ Hb, const float* __restrict__ S,
        const float* __restrict__ D,
        const int* __restrict__ off, const int* __restrict__ csr,
        float* __restrict__ out, int n) {
    int v = blockIdx.x * 4 + (threadIdx.x >> 6);
    int lane = threadIdx.x & 63;
    if (v >= n) return;
    int beg = off[v], end = off[v + 1];
    int deg = end - beg;
    float dv = D[v];
    int t = lane & 7, g = lane >> 3;
    float acc[8] = {};

    if (deg <= 64) {
        int sreg = 0;
        float e = -INFINITY;
        if (lane < deg) {
            sreg = csr[beg + lane];
            e = S[sreg] + dv;
            e = (e > 0.f) ? e : NEG_SLOPE * e;
        }
        float m = e;
        #pragma unroll
        for (int o = 32; o > 0; o >>= 1) m = fmaxf(m, __shfl_xor(m, o));
        float w = (lane < deg) ? __expf(e - m) : 0.f;
        float dsum = w;
        #pragma unroll
        for (int o = 32; o > 0; o >>= 1) dsum += __shfl_xor(dsum, o);
        w *= (1.f / dsum);
        for (int base = 0; base < deg; base += 8) {
            int jj = base + g;
            int jidx = (jj < deg) ? jj : 0;
            float a = __shfl(w, jidx);
            int s = __shfl(sreg, jidx);
            if (jj < deg) {
                uint4 u = *reinterpret_cast<const uint4*>(&Hb[(size_t)s * 32 + t * 4]);
                acc[0] = fmaf(a, __uint_as_float(u.x << 16), acc[0]);
                acc[1] = fmaf(a, __uint_as_float(u.x & 0xffff0000u), acc[1]);
                acc[2] = fmaf(a, __uint_as_float(u.y << 16), acc[2]);
                acc[3] = fmaf(a, __uint_as_float(u.y & 0xffff0000u), acc[3]);
                acc[4] = fmaf(a, __uint_as_float(u.z << 16), acc[4]);
                acc[5] = fmaf(a, __uint_as_float(u.z & 0xffff0000u), acc[5]);
                acc[6] = fmaf(a, __uint_as_float(u.w << 16), acc[6]);
                acc[7] = fmaf(a, __uint_as_float(u.w & 0xffff0000u), acc[7]);
            }
        }
    } else {
        // generic path (rare)
        float m = -INFINITY;
        for (int j = beg + lane; j < end; j += 64) {
            float e = S[csr[j]] + dv;
            e = (e > 0.f) ? e : NEG_SLOPE * e;
            m = fmaxf(m, e);
        }
        #pragma unroll
        for (int o = 32; o > 0; o >>= 1) m = fmaxf(m, __shfl_xor(m, o));
        float dsum = 0.f;
        for (int j = beg + lane; j < end; j += 64) {
            float e = S[csr[j]] + dv;
            e = (e > 0.f) ? e : NEG_SLOPE * e;
            dsum += __expf(e - m);
        }
        #pragma unroll
        for (int o = 32; o > 0; o >>= 1) dsum += __shfl_xor(dsum, o);
        float inv = 1.f / dsum;
        for (int base = 0; base < deg; base += 8) {
            int jj = base + g;
            if (jj < deg) {
                int s = csr[beg + jj];
                float e = S[s] + dv;
                e = (e > 0.f) ? e : NEG_SLOPE * e;
                float a = __expf(e - m) * inv;
                uint4 u = *reinterpret_cast<const uint4*>(&Hb[(size_t)s * 32 + t * 4]);
                acc[0] = fmaf(a, __uint_as_float(u.x << 16), acc[0]);
                acc[1] = fmaf(a, __uint_as_float(u.x & 0xffff0000u), acc[1]);
                acc[2] = fmaf(a, __uint_as_float(u.y << 16), acc[2]);
                acc[3] = fmaf(a, __uint_as_float(u.y & 0xffff0000u), acc[3]);
                acc[4] = fmaf(a, __uint_as_float(u.z << 16), acc[4]);
                acc[5] = fmaf(a, __uint_as_float(u.z & 0xffff0000u), acc[5]);
                acc[6] = fmaf(a, __uint_as_float(u.w << 16), acc[6]);
                acc[7] = fmaf(a, __uint_as_float(u.w & 0xffff0000u), acc[7]);
            }
        }
    }
    // reduce across the 8 edge-groups (g lives in lane bits 3..5)
    #pragma unroll
    for (int o = 8; o <= 32; o <<= 1) {
        #pragma unroll
        for (int k = 0; k < 8; ++k) acc[k] += __shfl_xor(acc[k], o);
    }
    if (g == 0) {
        float4 o0 = { acc[0], acc[1], acc[2], acc[3] };
        float4 o1 = { acc[4], acc[5], acc[6], acc[7] };
        *reinterpret_cast<float4*>(&out[(size_t)v * 64 + t * 8 + 0]) = o0;
        *reinterpret_cast<float4*>(&out[(size_t)v * 64 + t * 8 + 4]) = o1;
    }
}

// ---------------- driver ----------------

extern "C" void kernel_launch(void* const* d_in, const int* in_sizes, int n_in,
                              void* d_out, int out_size, void* d_ws, size_t ws_size,
                              hipStream_t stream) {
    const float* x   = (const float*)d_in[0];
    const int*   e   = (const int*)d_in[1];
    const float* W1  = (const float*)d_in[2];
    const float* as1 = (const float*)d_in[3];
    const float* ad1 = (const float*)d_in[4];
    const float* W2  = (const float*)d_in[5];
    const float* as2 = (const float*)d_in[6];
    const float* ad2 = (const float*)d_in[7];
    float* out = (float*)d_out;

    const int N = in_sizes[0] / 64;
    const int E = in_sizes[1] / 2;
    const int* src = e;
    const int* dst = e + E;

    // workspace layout (~24 MB)
    uint32* Hb  = (uint32*)d_ws;            // N*32 (bf16 H, 128B rows)
    float* S    = (float*)(Hb + (size_t)N * 32);  // N
    float* D    = S + N;                    // N
    int* deg    = (int*)(D + N);            // N
    int* off    = deg + N;                  // N+1
    int* pos    = off + N + 1;              // E
    int* csr    = pos + E;                  // E+N
    int* binc   = csr + (size_t)E + N;      // N
    int* bsum   = binc + N;                 // nblkN
    float* z1   = out;                      // layer-1 activations live in d_out

    const int B = 256;
    int nblkN = (N + B - 1) / B;
    int nblkE = (E + B - 1) / B;
    int nblkT = (E + N + B - 1) / B;
    int nblkG = (N + 63) / 64;
    int nblkW = (N + 3) / 4;

    // CSR: count (+slot assignment) -> scan -> [fill || gemm1]
    hipMemsetAsync(deg, 0, (size_t)N * sizeof(int), stream);
    count_pos_kernel<<<nblkE, B, 0, stream>>>(dst, deg, pos, E);
    scanA_kernel<<<nblkN, B, 0, stream>>>(deg, binc, bsum, N);
    scanB_kernel<<<1, 512, 0, stream>>>(bsum, nblkN);
    scanC_kernel<<<nblkN, B, 0, stream>>>(binc, bsum, off, N);

    gemm_fill_kernel<<<nblkG + nblkT, B, 0, stream>>>(
        x, W1, as1, ad1, Hb, S, D, N, src, dst, pos, off, csr, E, nblkG);

    aggregate_kernel<<<nblkW, B, 0, stream>>>(Hb, S, D, off, csr, z1, N);
    gemm_sd_kernel<<<nblkG, B, 0, stream>>>(z1, W2, as2, ad2, Hb, S, D, N);
    aggregate_kernel<<<nblkW, B, 0, stream>>>(Hb, S, D, off, csr, out, N);
}

// Round 9
// 172.131 us; speedup vs baseline: 3.4343x; 1.1868x over previous
//
#include <hip/hip_runtime.h>

#define NEG_SLOPE 0.2f

typedef unsigned int uint32;

// round-to-nearest-even pack of two floats into 2x bf16 in one uint
__device__ __forceinline__ uint32 pack2bf(float a, float b) {
    uint32 ua = __float_as_uint(a);
    uint32 ub = __float_as_uint(b);
    ua += 0x7fffu + ((ua >> 16) & 1u);
    ub += 0x7fffu + ((ub >> 16) & 1u);
    return (ua >> 16) | (ub & 0xffff0000u);
}

// ---------------- CSR construction ----------------

__global__ void init_deg_kernel(int* __restrict__ deg, int n) {
    int i = blockIdx.x * blockDim.x + threadIdx.x;
    if (i < n) deg[i] = 0;
}

// Single atomic pass: each edge grabs its slot during counting.
__global__ void count_pos_kernel(const int* __restrict__ dst, int* __restrict__ deg,
                                 int* __restrict__ pos, int E) {
    int i = blockIdx.x * blockDim.x + threadIdx.x;
    if (i < E) pos[i] = atomicAdd(&deg[dst[i]], 1);
}

// block-level inclusive scan of (deg[i]+1) — +1 reserves the self-loop slot
__global__ void scanA_kernel(const int* __restrict__ deg, int* __restrict__ binc,
                             int* __restrict__ bsum, int n) {
    __shared__ int ws[4];
    int tid = threadIdx.x;
    int i = blockIdx.x * 256 + tid;
    int lane = tid & 63, wid = tid >> 6;
    int x = (i < n) ? (deg[i] + 1) : 0;
    #pragma unroll
    for (int d = 1; d < 64; d <<= 1) { int t = __shfl_up(x, d); if (lane >= d) x += t; }
    if (lane == 63) ws[wid] = x;
    __syncthreads();
    int wofs = 0;
    for (int w = 0; w < wid; ++w) wofs += ws[w];
    x += wofs;
    if (i < n) binc[i] = x;
    if (tid == 255) bsum[blockIdx.x] = x;
}

// single-block inclusive scan of block sums, in place
__global__ void scanB_kernel(int* __restrict__ bsum, int nb) {
    __shared__ int ws[8];
    __shared__ int run_s;
    int tid = threadIdx.x;
    int lane = tid & 63, wid = tid >> 6;
    if (tid == 0) run_s = 0;
    __syncthreads();
    for (int base = 0; base < nb; base += 512) {
        int i = base + tid;
        int v = (i < nb) ? bsum[i] : 0;
        int x = v;
        #pragma unroll
        for (int d = 1; d < 64; d <<= 1) { int t = __shfl_up(x, d); if (lane >= d) x += t; }
        if (lane == 63) ws[wid] = x;
        __syncthreads();
        int wofs = 0;
        for (int w = 0; w < wid; ++w) wofs += ws[w];
        x += wofs;
        int run = run_s;
        if (i < nb) bsum[i] = x + run;
        __syncthreads();
        if (tid == 511) run_s = run + x;
        __syncthreads();
    }
}

__global__ void scanC_kernel(const int* __restrict__ binc, const int* __restrict__ bsumS,
                             int* __restrict__ off, int n) {
    int i = blockIdx.x * 256 + threadIdx.x;
    if (i < n) off[i + 1] = binc[i] + (blockIdx.x ? bsumS[blockIdx.x - 1] : 0);
    if (i == 0) off[0] = 0;
}

// ---------------- shared GEMM body: H(bf16) = X@W, S/D epilogue ----------------
// 64x64 tile, 4x4 micro-tile, k stepped by 4 with float4 X-fragment reads.

__device__ __forceinline__ void gemm_body(
        const float* __restrict__ X, const float* __restrict__ W,
        const float* __restrict__ a_src, const float* __restrict__ a_dst,
        uint32* __restrict__ Hb, float* __restrict__ S, float* __restrict__ D,
        int n, int tile, float (*Xs)[68], float* Wl) {
    int tid = threadIdx.x;
    int row0 = tile * 64;
    {
        const float4* W4 = reinterpret_cast<const float4*>(W);
        float4* Wl4 = reinterpret_cast<float4*>(Wl);
        for (int i = tid; i < 1024; i += 256) Wl4[i] = W4[i];
    }
    {
        for (int i = tid; i < 1024; i += 256) {
            int r = i >> 4;
            int c4 = (i & 15) * 4;
            int row = row0 + r;
            float4 xv = {0.f, 0.f, 0.f, 0.f};
            if (row < n) xv = *reinterpret_cast<const float4*>(&X[(size_t)row * 64 + c4]);
            *reinterpret_cast<float4*>(&Xs[r][c4]) = xv;
        }
    }
    __syncthreads();

    int c4 = (tid & 15) * 4;
    int r4 = (tid >> 4) * 4;
    float acc[4][4] = {};
    #pragma unroll 4
    for (int k0 = 0; k0 < 64; k0 += 4) {
        float x4[4][4];
        #pragma unroll
        for (int i = 0; i < 4; ++i)
            *reinterpret_cast<float4*>(x4[i]) =
                *reinterpret_cast<const float4*>(&Xs[r4 + i][k0]);
        #pragma unroll
        for (int j = 0; j < 4; ++j) {
            float4 wv = *reinterpret_cast<const float4*>(&Wl[(k0 + j) * 64 + c4]);
            #pragma unroll
            for (int i = 0; i < 4; ++i) {
                acc[i][0] = fmaf(x4[i][j], wv.x, acc[i][0]);
                acc[i][1] = fmaf(x4[i][j], wv.y, acc[i][1]);
                acc[i][2] = fmaf(x4[i][j], wv.z, acc[i][2]);
                acc[i][3] = fmaf(x4[i][j], wv.w, acc[i][3]);
            }
        }
    }
    #pragma unroll
    for (int i = 0; i < 4; ++i) {
        int row = row0 + r4 + i;
        if (row < n) {
            uint2 p;
            p.x = pack2bf(acc[i][0], acc[i][1]);
            p.y = pack2bf(acc[i][2], acc[i][3]);
            *reinterpret_cast<uint2*>(&Hb[(size_t)row * 32 + (c4 >> 1)]) = p;
        }
    }
    float4 av = *reinterpret_cast<const float4*>(&a_src[c4]);
    float4 bv = *reinterpret_cast<const float4*>(&a_dst[c4]);
    #pragma unroll
    for (int i = 0; i < 4; ++i) {
        float ps = acc[i][0] * av.x + acc[i][1] * av.y + acc[i][2] * av.z + acc[i][3] * av.w;
        float pd = acc[i][0] * bv.x + acc[i][1] * bv.y + acc[i][2] * bv.z + acc[i][3] * bv.w;
        #pragma unroll
        for (int o = 1; o < 16; o <<= 1) {
            ps += __shfl_xor(ps, o);
            pd += __shfl_xor(pd, o);
        }
        int row = row0 + r4 + i;
        if ((tid & 15) == 0 && row < n) { S[row] = ps; D[row] = pd; }
    }
}

// ---------------- fused: CSR fill (scatter)  +  layer-1 GEMM ----------------

__global__ __launch_bounds__(256) void gemm_fill_kernel(
        const float* __restrict__ X, const float* __restrict__ W,
        const float* __restrict__ a_src, const float* __restrict__ a_dst,
        uint32* __restrict__ Hb, float* __restrict__ S, float* __restrict__ D, int n,
        const int* __restrict__ src, const int* __restrict__ dst,
        const int* __restrict__ pos, const int* __restrict__ off,
        int* __restrict__ csr, int E, int nblkG) {
    __shared__ float Xs[64][68];
    __shared__ float Wl[64 * 64];

    if (blockIdx.x >= nblkG) {
        int i = (blockIdx.x - nblkG) * 256 + threadIdx.x;
        int total = E + n;
        if (i >= total) return;
        if (i < E) {
            int idx = off[dst[i]] + pos[i];
            if ((unsigned)idx < (unsigned)total) csr[idx] = src[i];  // OOB-proof scatter
        } else {
            int v = i - E;
            int idx = off[v + 1] - 1;                // self-loop in reserved last slot
            if ((unsigned)idx < (unsigned)total) csr[idx] = v;
        }
        return;
    }
    gemm_body(X, W, a_src, a_dst, Hb, S, D, n, blockIdx.x, Xs, Wl);
}

// ---------------- plain GEMM + S/D (layer 2) ----------------

__global__ __launch_bounds__(256) void gemm_sd_kernel(
        const float* __restrict__ X, const float* __restrict__ W,
        const float* __restrict__ a_src, const float* __restrict__ a_dst,
        uint32* __restrict__ Hb, float* __restrict__ S, float* __restrict__ D, int n) {
    __shared__ float Xs[64][68];
    __shared__ float Wl[64 * 64];
    gemm_body(X, W, a_src, a_dst, Hb, S, D, n, blockIdx.x, Xs, Wl);
}

// ---------------- per-node softmax + aggregate ----------------
// 2 nodes per wave: 32-lane segment per node. Softmax over up to 32 edges
// (lane = edge), gather with 4 edge-groups x 8 lanes x uint4 (128B bf16 row).
// Gather trip count is wave-uniform (max over both segments) so the loop
// never diverges between segments; pad iterations contribute a=0.

__global__ __launch_bounds__(256) void aggregate_kernel(
        const uint32* __restrict__ Hb, const float* __restrict__ S,
        const float* __restrict__ D,
        const int* __restrict__ off, const int* __restrict__ csr,
        float* __restrict__ out, int n) {
    int tid = threadIdx.x;
    int lane = tid & 63;
    int sl = lane & 31;
    int seg = lane >> 5;
    int wv_ = tid >> 6;
    int v = blockIdx.x * 8 + wv_ * 2 + seg;
    bool valid = v < n;
    int beg = 0, deg = 0;
    float dv = 0.f;
    if (valid) { beg = off[v]; deg = off[v + 1] - beg; dv = D[v]; }

    if (__all(deg <= 32)) {
        // ---- fast path ----
        int sreg = 0;
        float e = -INFINITY;
        if (sl < deg) {
            int s0 = csr[beg + sl];
            sreg = ((unsigned)s0 < (unsigned)n) ? s0 : 0;   // clamp: no wild gathers
            float t = S[sreg] + dv;
            e = (t > 0.f) ? t : NEG_SLOPE * t;
        }
        float m = e;
        #pragma unroll
        for (int o = 16; o > 0; o >>= 1) m = fmaxf(m, __shfl_xor(m, o));
        float w = (sl < deg) ? __expf(e - m) : 0.f;
        float dsum = w;
        #pragma unroll
        for (int o = 16; o > 0; o >>= 1) dsum += __shfl_xor(dsum, o);
        w *= (1.f / dsum);

        int t8 = sl & 7, g = sl >> 3;
        int segbase = seg << 5;
        float acc[8] = {};
        int dmax = max(deg, __shfl_xor(deg, 32));   // wave-uniform trip count
        int nit = (dmax + 3) >> 2;
        for (int it = 0; it < nit; ++it) {
            int jj = (it << 2) + g;
            int jidx = (jj < deg) ? jj : ((deg > 0) ? (deg - 1) : 0);
            float a = __shfl(w, segbase + jidx);
            int s = __shfl(sreg, segbase + jidx);
            a = (jj < deg) ? a : 0.f;
            uint4 u = *reinterpret_cast<const uint4*>(&Hb[((size_t)s << 5) + (t8 << 2)]);
            acc[0] = fmaf(a, __uint_as_float(u.x << 16), acc[0]);
            acc[1] = fmaf(a, __uint_as_float(u.x & 0xffff0000u), acc[1]);
            acc[2] = fmaf(a, __uint_as_float(u.y << 16), acc[2]);
            acc[3] = fmaf(a, __uint_as_float(u.y & 0xffff0000u), acc[3]);
            acc[4] = fmaf(a, __uint_as_float(u.z << 16), acc[4]);
            acc[5] = fmaf(a, __uint_as_float(u.z & 0xffff0000u), acc[5]);
            acc[6] = fmaf(a, __uint_as_float(u.w << 16), acc[6]);
            acc[7] = fmaf(a, __uint_as_float(u.w & 0xffff0000u), acc[7]);
        }
        // reduce across the 4 edge-groups (within 32-lane segment)
        #pragma unroll
        for (int o = 8; o <= 16; o <<= 1) {
            #pragma unroll
            for (int k = 0; k < 8; ++k) acc[k] += __shfl_xor(acc[k], o);
        }
        if (valid && g == 0) {
            float4 o0 = { acc[0], acc[1], acc[2], acc[3] };
            float4 o1 = { acc[4], acc[5], acc[6], acc[7] };
            *reinterpret_cast<float4*>(&out[(size_t)v * 64 + (t8 << 3)]) = o0;
            *reinterpret_cast<float4*>(&out[(size_t)v * 64 + (t8 << 3) + 4]) = o1;
        }
    } else {
        // ---- generic path (deg > 32 somewhere in this wave; essentially never) ----
        for (int it = 0; it < 2; ++it) {
            int vv = blockIdx.x * 8 + wv_ * 2 + it;
            if (vv >= n) continue;
            int beg2 = off[vv], end2 = off[vv + 1];
            int deg2 = end2 - beg2;
            float dv2 = D[vv];
            float m = -INFINITY;
            for (int j = beg2 + lane; j < end2; j += 64) {
                int s0 = csr[j]; s0 = ((unsigned)s0 < (unsigned)n) ? s0 : 0;
                float t = S[s0] + dv2;
                t = (t > 0.f) ? t : NEG_SLOPE * t;
                m = fmaxf(m, t);
            }
            #pragma unroll
            for (int o = 32; o > 0; o >>= 1) m = fmaxf(m, __shfl_xor(m, o));
            float dsum = 0.f;
            for (int j = beg2 + lane; j < end2; j += 64) {
                int s0 = csr[j]; s0 = ((unsigned)s0 < (unsigned)n) ? s0 : 0;
                float t = S[s0] + dv2;
                t = (t > 0.f) ? t : NEG_SLOPE * t;
                dsum += __expf(t - m);
            }
            #pragma unroll
            for (int o = 32; o > 0; o >>= 1) dsum += __shfl_xor(dsum, o);
            float inv = 1.f / dsum;
            int t8 = lane & 7, g8 = lane >> 3;
            float acc[8] = {};
            for (int b = 0; b < deg2; b += 8) {
                int jj = b + g8;
                if (jj < deg2) {
                    int s = csr[beg2 + jj]; s = ((unsigned)s < (unsigned)n) ? s : 0;
                    float t = S[s] + dv2;
                    t = (t > 0.f) ? t : NEG_SLOPE * t;
                    float a = __expf(t - m) * inv;
                    uint4 u = *reinterpret_cast<const uint4*>(&Hb[((size_t)s << 5) + (t8 << 2)]);
                    acc[0] = fmaf(a, __uint_as_float(u.x << 16), acc[0]);
                    acc[1] = fmaf(a, __uint_as_float(u.x & 0xffff0000u), acc[1]);
                    acc[2] = fmaf(a, __uint_as_float(u.y << 16), acc[2]);
                    acc[3] = fmaf(a, __uint_as_float(u.y & 0xffff0000u), acc[3]);
                    acc[4] = fmaf(a, __uint_as_float(u.z << 16), acc[4]);
                    acc[5] = fmaf(a, __uint_as_float(u.z & 0xffff0000u), acc[5]);
                    acc[6] = fmaf(a, __uint_as_float(u.w << 16), acc[6]);
                    acc[7] = fmaf(a, __uint_as_float(u.w & 0xffff0000u), acc[7]);
                }
            }
            #pragma unroll
            for (int o = 8; o <= 32; o <<= 1) {
                #pragma unroll
                for (int k = 0; k < 8; ++k) acc[k] += __shfl_xor(acc[k], o);
            }
            if (g8 == 0) {
                float4 o0 = { acc[0], acc[1], acc[2], acc[3] };
                float4 o1 = { acc[4], acc[5], acc[6], acc[7] };
                *reinterpret_cast<float4*>(&out[(size_t)vv * 64 + (t8 << 3)]) = o0;
                *reinterpret_cast<float4*>(&out[(size_t)vv * 64 + (t8 << 3) + 4]) = o1;
            }
        }
    }
}

// ---------------- driver ----------------

extern "C" void kernel_launch(void* const* d_in, const int* in_sizes, int n_in,
                              void* d_out, int out_size, void* d_ws, size_t ws_size,
                              hipStream_t stream) {
    const float* x   = (const float*)d_in[0];
    const int*   e   = (const int*)d_in[1];
    const float* W1  = (const float*)d_in[2];
    const float* as1 = (const float*)d_in[3];
    const float* ad1 = (const float*)d_in[4];
    const float* W2  = (const float*)d_in[5];
    const float* as2 = (const float*)d_in[6];
    const float* ad2 = (const float*)d_in[7];
    float* out = (float*)d_out;

    const int N = in_sizes[0] / 64;
    const int E = in_sizes[1] / 2;
    const int* src = e;
    const int* dst = e + E;

    // workspace layout (~49 MB); d_out is written only by the final kernel
    uint32* Hb  = (uint32*)d_ws;                  // N*32 (bf16 H, 128B rows)
    float* z1   = (float*)(Hb + (size_t)N * 32);  // N*64 layer-1 activations
    float* S    = z1 + (size_t)N * 64;            // N
    float* D    = S + N;                          // N
    int* deg    = (int*)(D + N);                  // N
    int* off    = deg + N;                        // N+1
    int* pos    = off + N + 1;                    // E
    int* csr    = pos + E;                        // E+N
    int* binc   = csr + (size_t)E + N;            // N
    int* bsum   = binc + N;                       // nblkN

    const int B = 256;
    int nblkN = (N + B - 1) / B;
    int nblkE = (E + B - 1) / B;
    int nblkT = (E + N + B - 1) / B;
    int nblkG = (N + 63) / 64;
    int nblkA = (N + 7) / 8;     // aggregate: 8 nodes per block (2 per wave)

    // CSR: init -> count (+slot assignment) -> scan -> [fill || gemm1]
    init_deg_kernel<<<nblkN, B, 0, stream>>>(deg, N);
    count_pos_kernel<<<nblkE, B, 0, stream>>>(dst, deg, pos, E);
    scanA_kernel<<<nblkN, B, 0, stream>>>(deg, binc, bsum, N);
    scanB_kernel<<<1, 512, 0, stream>>>(bsum, nblkN);
    scanC_kernel<<<nblkN, B, 0, stream>>>(binc, bsum, off, N);

    gemm_fill_kernel<<<nblkG + nblkT, B, 0, stream>>>(
        x, W1, as1, ad1, Hb, S, D, N, src, dst, pos, off, csr, E, nblkG);

    aggregate_kernel<<<nblkA, B, 0, stream>>>(Hb, S, D, off, csr, z1, N);
    gemm_sd_kernel<<<nblkG, B, 0, stream>>>(z1, W2, as2, ad2, Hb, S, D, N);
    aggregate_kernel<<<nblkA, B, 0, stream>>>(Hb, S, D, off, csr, out, N);
}